// Round 2
// baseline (196.533 us; speedup 1.0000x reference)
//
#include <hip/hip_runtime.h>
#include <stdint.h>

#define NIMG 32
#define H 1024
#define W 1024
#define BH 73
#define BW 73
#define NCHUNK (NIMG * BH)        // 2336 chunks; chunk = n*73 + by
#define TOTAL (NIMG * BH * BW)    // 170528
#define BS 14                     // block stride
#define KW 16                     // pool window
#define G 4                       // strips per pool block (vertical fusion)
#define NSB 19                    // ceil(BH/G) super-strips per image
#define NPOOL (NIMG * NSB)        // 608 pool blocks (608 = 8*76, clean XCD swizzle)
#define NROWS (G * BS + 2)        // 58 rows per super-strip

// ---------------------------------------------------------------------------
// Kernel A: per-(n,sb) SUPER-strip max-pool covering G=4 vertically adjacent
// 16-row windows (stride 14). Each row is loaded exactly ONCE per block into
// 4 in-register sliding-window accumulators (rows shared by two windows feed
// both), eliminating the 2-row/window overfetch of the 1-strip version:
// 58 rows vs 64 -> fetch 153 MB -> ~140 MB. Rows stream in batches of 8
// independent float4 loads (MLP). XCD-chunked swizzle keeps vertically
// adjacent super-strips on the same XCD L2 for the remaining 2-row overlap.
// Writes flags (1B/block-col), per-chunk counts, and prefills the output
// region with the fill triple (32,73,73).
// ---------------------------------------------------------------------------
__global__ __launch_bounds__(256) void pool_kernel(const float* __restrict__ mask,
                                                   uint8_t* __restrict__ flags,
                                                   int* __restrict__ counts,
                                                   int* __restrict__ out_idx) {
    int bid = blockIdx.x;
    // bijective XCD-chunked swizzle: hw block b -> xcd b%8; give each XCD a
    // contiguous range of logical super-chunks (608 = 8 * 76 exactly)
    int sc = (bid & 7) * (NPOOL / 8) + (bid >> 3);
    int n  = sc / NSB;
    int sb = sc - n * NSB;
    int cb = n * BH + sb * G;                       // first chunk of this block
    int kmax = BH - sb * G; kmax = (kmax > G) ? G : kmax;   // 4, or 1 for sb=18
    const float* img = mask + (size_t)n * (H * W);
    int t = threadIdx.x;
    int lane = t & 63;
    int wave = t >> 6;

    __shared__ float colmax[G][W];                  // 16 KB
    __shared__ int sred[G][4];

    const int Y0 = sb * (G * BS) - 1;               // first row (may be -1)
    float4 win[G];
#pragma unroll
    for (int k = 0; k < G; ++k)
        win[k] = make_float4(-3.0e38f, -3.0e38f, -3.0e38f, -3.0e38f);

    // stream 58 rows, batches of 8 fully-independent float4 loads (last = 2).
    // Row index clamped to [0, H-1]: top clamp dups row 0 (no-op under max);
    // bottom clamp only fires for sb=18's unused windows k>=1 (L1-hot dup).
    float4 v[8];
#pragma unroll
    for (int b = 0; b < 8; ++b) {
        const int nb = (b == 7) ? (NROWS - 56) : 8;
#pragma unroll
        for (int j = 0; j < 8; ++j) {
            if (j < nb) {
                int y = Y0 + b * 8 + j;
                y = (y < 0) ? 0 : y;
                y = (y > H - 1) ? (H - 1) : y;
                v[j] = ((const float4*)(img + (size_t)y * W))[t];
            }
        }
#pragma unroll
        for (int j = 0; j < 8; ++j) {
            if (j < nb) {
                const int r = b * 8 + j;            // compile-time after unroll
#pragma unroll
                for (int k = 0; k < G; ++k) {
                    // window k owns rows [14k, 14k+15]; rows 14k+14,14k+15
                    // are shared with window k+1 (both guards true)
                    if (r >= k * BS && r < k * BS + KW) {
                        win[k].x = fmaxf(win[k].x, v[j].x);
                        win[k].y = fmaxf(win[k].y, v[j].y);
                        win[k].z = fmaxf(win[k].z, v[j].z);
                        win[k].w = fmaxf(win[k].w, v[j].w);
                    }
                }
            }
        }
    }
#pragma unroll
    for (int k = 0; k < G; ++k) ((float4*)colmax[k])[t] = win[k];

    // prefill this block's kmax*219-int output region with (32,73,73)
    // (independent global writes, overlapped with the LDS barrier)
    {
        int npre = kmax * (BW * 3);
        int base = cb * (BW * 3);                   // divisible by 3
        for (int p = t; p < npre; p += 256)
            out_idx[base + p] = ((p % 3) == 0) ? NIMG : BH;   // BH == BW == 73
    }
    __syncthreads();

#pragma unroll
    for (int k = 0; k < G; ++k) {
        int flag = 0;
        if (t < BW) {
            int x0 = t * BS - 1;
            float m = colmax[k][x0 < 0 ? 0 : x0];
#pragma unroll
            for (int c = 1; c < KW; ++c)
                m = fmaxf(m, colmax[k][x0 + c]);    // x0+c in [0, 1022]
            flag = (m > 0.5f) ? 1 : 0;
            if (k < kmax) flags[(cb + k) * BW + t] = (uint8_t)flag;
        }
        unsigned long long bmask = __ballot(flag);
        if (lane == 0) sred[k][wave] = __popcll(bmask);
    }
    __syncthreads();
    if (t < kmax)
        counts[cb + t] = sred[t][0] + sred[t][1] + sred[t][2] + sred[t][3];
}

// ---------------------------------------------------------------------------
// Kernel B (unchanged): per-chunk exclusive prefix via block-parallel
// reduction over the 9 KB counts array (L2-hot), ballot rank, scatter
// triples. Block 0 also writes the total count.
// ---------------------------------------------------------------------------
__global__ __launch_bounds__(128) void scatter_kernel(const uint8_t* __restrict__ flags,
                                                      const int* __restrict__ counts,
                                                      int* __restrict__ out_idx) {
    int chunk = blockIdx.x;
    int n  = chunk / BH;
    int by = chunk - n * BH;
    int t = threadIdx.x;              // 0..127
    int lane = t & 63;
    int wave = t >> 6;
    __shared__ int sred[2];
    __shared__ int w0cnt;

    int flag = (t < BW) ? (int)flags[chunk * BW + t] : 0;

    // exclusive prefix: block-parallel sum of counts[0..chunk)
    int local = 0;
    for (int i = t; i < chunk; i += 128) local += counts[i];
    local += __shfl_down(local, 32);
    local += __shfl_down(local, 16);
    local += __shfl_down(local, 8);
    local += __shfl_down(local, 4);
    local += __shfl_down(local, 2);
    local += __shfl_down(local, 1);
    if (lane == 0) sred[wave] = local;
    unsigned long long b = __ballot(flag);
    if (t == 0) w0cnt = __popcll(b);
    __syncthreads();
    int cbase = sred[0] + sred[1];
    int pos = __popcll(b & ((1ull << lane) - 1ull)) + ((t >= 64) ? w0cnt : 0);
    if (flag) {
        int o = (cbase + pos) * 3;
        out_idx[o]     = n;
        out_idx[o + 1] = by;
        out_idx[o + 2] = t;
    }

    // total count -> out[TOTAL*3] (block 0 only)
    if (chunk == 0) {
        int tot = 0;
        for (int i = t; i < NCHUNK; i += 128) tot += counts[i];
        tot += __shfl_down(tot, 32);
        tot += __shfl_down(tot, 16);
        tot += __shfl_down(tot, 8);
        tot += __shfl_down(tot, 4);
        tot += __shfl_down(tot, 2);
        tot += __shfl_down(tot, 1);
        __syncthreads();
        if (lane == 0) sred[wave] = tot;
        __syncthreads();
        if (t == 0) out_idx[(size_t)TOTAL * 3] = sred[0] + sred[1];
    }
}

extern "C" void kernel_launch(void* const* d_in, const int* in_sizes, int n_in,
                              void* d_out, int out_size, void* d_ws, size_t ws_size,
                              hipStream_t stream) {
    const float* mask = (const float*)d_in[0];
    int* out = (int*)d_out;

    uint8_t* flags = (uint8_t*)d_ws;                    // 170528 B
    int* counts = (int*)((char*)d_ws + 170624);         // 2336 ints

    pool_kernel<<<NPOOL, 256, 0, stream>>>(mask, flags, counts, out);
    scatter_kernel<<<NCHUNK, 128, 0, stream>>>(flags, counts, out);
}

// Round 3
// 192.884 us; speedup vs baseline: 1.0189x; 1.0189x over previous
//
#include <hip/hip_runtime.h>
#include <stdint.h>

#define NIMG 32
#define H 1024
#define W 1024
#define BH 73
#define BW 73
#define NCHUNK (NIMG * BH)        // 2336 chunks; chunk = n*73 + by  (2336 = 8*292)
#define TOTAL (NIMG * BH * BW)    // 170528
#define BS 14                     // block stride
#define KW 16                     // pool window
#define CPB 4                     // chunks per scatter block (2336/4 = 584 exact)

// ---------------------------------------------------------------------------
// Kernel A: per-(n,by) strip max-pool (round-0 proven structure: 2336 fine-
// grained blocks, ~50 VGPR, full occupancy). Row loads issued in two batches
// of 8 fully-independent float4 loads (row 0 dup under clamp is a no-op for
// max). NEW: bijective XCD-chunked blockIdx swizzle (2336 = 8*292) so
// vertically adjacent strips (sharing a 2-row halo) run back-to-back on the
// same XCD -> halo reads hit that XCD's L2 instead of L3/HBM.
// Writes flags (1B/col), per-chunk counts, prefills output with (32,73,73).
// ---------------------------------------------------------------------------
__global__ __launch_bounds__(256) void pool_kernel(const float* __restrict__ mask,
                                                   uint8_t* __restrict__ flags,
                                                   int* __restrict__ counts,
                                                   int* __restrict__ out_idx) {
    int bid = blockIdx.x;
    int chunk = (bid & 7) * (NCHUNK / 8) + (bid >> 3);   // bijective XCD swizzle
    int n  = chunk / BH;
    int by = chunk - n * BH;
    const float* img = mask + (size_t)n * (H * W);
    int t = threadIdx.x;
    int lane = t & 63;
    int wave = t >> 6;
    __shared__ float colmax[W];
    __shared__ int sred[4];

    int y0 = by * BS - 1;
    float4 v[8];
    // batch 0: rows 0..7 (clamped), 8 independent loads in flight
#pragma unroll
    for (int r = 0; r < 8; ++r) {
        int y = y0 + r;
        y = (y < 0) ? 0 : y;              // dup row 0: harmless under max
        v[r] = ((const float4*)(img + (size_t)y * W))[t];
    }
    float4 acc = v[0];
#pragma unroll
    for (int r = 1; r < 8; ++r) {
        acc.x = fmaxf(acc.x, v[r].x);
        acc.y = fmaxf(acc.y, v[r].y);
        acc.z = fmaxf(acc.z, v[r].z);
        acc.w = fmaxf(acc.w, v[r].w);
    }
    // batch 1: rows 8..15 (no clamp needed; y0+8 >= 7, y0+15 <= 1022)
#pragma unroll
    for (int r = 0; r < 8; ++r) {
        v[r] = ((const float4*)(img + (size_t)(y0 + 8 + r) * W))[t];
    }
#pragma unroll
    for (int r = 0; r < 8; ++r) {
        acc.x = fmaxf(acc.x, v[r].x);
        acc.y = fmaxf(acc.y, v[r].y);
        acc.z = fmaxf(acc.z, v[r].z);
        acc.w = fmaxf(acc.w, v[r].w);
    }
    ((float4*)colmax)[t] = acc;
    __syncthreads();

    int flag = 0;
    if (t < BW) {
        int x0 = t * BS - 1;
        float m = colmax[x0 < 0 ? 0 : x0];
#pragma unroll
        for (int c = 1; c < KW; ++c) {
            m = fmaxf(m, colmax[x0 + c]);  // x0+c in [0, 1022]
        }
        flag = (m > 0.5f) ? 1 : 0;
        flags[chunk * BW + t] = (uint8_t)flag;
    }
    // prefill this chunk's 219-int output region with (32,73,73)
    if (t < BW * 3) {
        int p = chunk * (BW * 3) + t;      // 219 % 3 == 0 -> p%3 == t%3
        out_idx[p] = ((t % 3) == 0) ? NIMG : BH;   // BH == BW == 73
    }
    unsigned long long b = __ballot(flag);
    if (lane == 0) sred[wave] = __popcll(b);
    __syncthreads();
    if (t == 0) counts[chunk] = sred[0] + sred[1] + sred[2] + sred[3];
}

// ---------------------------------------------------------------------------
// Kernel B: 584 blocks x 256 threads; each block handles CPB=4 chunks, one
// wave per chunk. Block-parallel sum of counts[0..cb) (L2-hot 9 KB array,
// 4x less traffic than per-chunk blocks), then each wave adds its <=3-int
// intra-block prefix. 73 columns per chunk covered by two 64-lane ballots
// (cols 0..63, then 64..72) -> rank -> scatter triples. Block 0 also writes
// the total count.
// ---------------------------------------------------------------------------
__global__ __launch_bounds__(256) void scatter_kernel(const uint8_t* __restrict__ flags,
                                                      const int* __restrict__ counts,
                                                      int* __restrict__ out_idx) {
    int cb = blockIdx.x * CPB;
    int t = threadIdx.x;              // 0..255
    int lane = t & 63;
    int wave = t >> 6;                // 0..3 -> chunk cb+wave
    __shared__ int sred[4];

    // block-wide exclusive prefix: sum of counts[0..cb)
    int local = 0;
    for (int i = t; i < cb; i += 256) local += counts[i];
    local += __shfl_down(local, 32);
    local += __shfl_down(local, 16);
    local += __shfl_down(local, 8);
    local += __shfl_down(local, 4);
    local += __shfl_down(local, 2);
    local += __shfl_down(local, 1);
    if (lane == 0) sred[wave] = local;
    __syncthreads();
    int base = sred[0] + sred[1] + sred[2] + sred[3];

    int chunk = cb + wave;
    int n  = chunk / BH;
    int by = chunk - n * BH;
    // intra-block prefix: counts of the preceding waves' chunks (L1/L2-hot)
#pragma unroll
    for (int i = 0; i < CPB - 1; ++i)
        if (i < wave) base += counts[cb + i];

    const uint8_t* fc = flags + chunk * BW;
    int f0 = (int)fc[lane];                                  // cols 0..63
    int f1 = (lane < BW - 64) ? (int)fc[64 + lane] : 0;      // cols 64..72
    unsigned long long b0 = __ballot(f0);
    unsigned long long b1 = __ballot(f1);
    unsigned long long lt = (1ull << lane) - 1ull;
    if (f0) {
        int o = (base + __popcll(b0 & lt)) * 3;
        out_idx[o]     = n;
        out_idx[o + 1] = by;
        out_idx[o + 2] = lane;
    }
    if (f1) {
        int o = (base + __popcll(b0) + __popcll(b1 & lt)) * 3;
        out_idx[o]     = n;
        out_idx[o + 1] = by;
        out_idx[o + 2] = 64 + lane;
    }

    // total count -> out[TOTAL*3] (block 0 only)
    if (blockIdx.x == 0) {
        int tot = 0;
        for (int i = t; i < NCHUNK; i += 256) tot += counts[i];
        tot += __shfl_down(tot, 32);
        tot += __shfl_down(tot, 16);
        tot += __shfl_down(tot, 8);
        tot += __shfl_down(tot, 4);
        tot += __shfl_down(tot, 2);
        tot += __shfl_down(tot, 1);
        __syncthreads();               // all reads of sred (base) are done
        if (lane == 0) sred[wave] = tot;
        __syncthreads();
        if (t == 0) out_idx[(size_t)TOTAL * 3] = sred[0] + sred[1] + sred[2] + sred[3];
    }
}

extern "C" void kernel_launch(void* const* d_in, const int* in_sizes, int n_in,
                              void* d_out, int out_size, void* d_ws, size_t ws_size,
                              hipStream_t stream) {
    const float* mask = (const float*)d_in[0];
    int* out = (int*)d_out;

    uint8_t* flags = (uint8_t*)d_ws;                    // 170528 B
    int* counts = (int*)((char*)d_ws + 170624);         // 2336 ints

    pool_kernel<<<NCHUNK, 256, 0, stream>>>(mask, flags, counts, out);
    scatter_kernel<<<NCHUNK / CPB, 256, 0, stream>>>(flags, counts, out);
}